// Round 2
// baseline (403.035 us; speedup 1.0000x reference)
//
#include <hip/hip_runtime.h>
#include <hip/hip_bf16.h>
#include <math.h>

typedef float  f32x4 __attribute__((ext_vector_type(4)));
typedef short  s16x8 __attribute__((ext_vector_type(8)));
typedef __bf16 bf16x8 __attribute__((ext_vector_type(8)));
typedef int    i32x4 __attribute__((ext_vector_type(4)));
typedef unsigned int u32;
typedef unsigned short u16;
typedef unsigned long long u64;

#define DEVI static __device__ __forceinline__

DEVI u16 f2bf(float f) {
  u32 x = __builtin_bit_cast(u32, f);
  x += 0x7fffu + ((x >> 16) & 1u);   // RNE
  return (u16)(x >> 16);
}

DEVI f32x4 mfma_bf16(s16x8 a, s16x8 b, f32x4 c) {
  return __builtin_amdgcn_mfma_f32_16x16x32_bf16(
      __builtin_bit_cast(bf16x8, a), __builtin_bit_cast(bf16x8, b), c, 0, 0, 0);
}

DEVI void gload_lds16(const void* g, void* l) {
  __builtin_amdgcn_global_load_lds(
      (const __attribute__((address_space(1))) void*)g,
      (__attribute__((address_space(3))) void*)l, 16, 0, 0);
}

// ---------------------------------------------------------------------------
// Kernel 1: QKV projections.  z=0: Q=xq*wq^T+bq (scaled 1/8, bf16 [tok][512])
//           z=1: K           z=2: V written transposed as VT[b*512+h*64+d][s]
// grid (128, 4, 3), block 256.
// ---------------------------------------------------------------------------
__global__ __launch_bounds__(256, 2)
void qkv_proj(const float* __restrict__ xq, const float* __restrict__ xkv,
              const float* __restrict__ wq, const float* __restrict__ bq,
              const float* __restrict__ wk, const float* __restrict__ bk,
              const float* __restrict__ wv, const float* __restrict__ bv,
              u16* __restrict__ Qo, u16* __restrict__ Ko, u16* __restrict__ VTo)
{
  __shared__ char smem[128 * 272];      // staging A[0,8K) B[8K,16K); V-transpose buf
  char* lds_a = smem;
  char* lds_b = smem + 8192;

  const int z = blockIdx.z;
  const float* X  = (z == 0) ? xq : xkv;
  const float* W  = (z == 0) ? wq : (z == 1 ? wk : wv);
  const float* Bv = (z == 0) ? bq : (z == 1 ? bk : bv);

  const int m0 = blockIdx.x * 128, n0 = blockIdx.y * 128;
  const int t = threadIdx.x, lane = t & 63, w = t >> 6;
  const int wr = w >> 1, wc = w & 1, g = lane >> 4, q15 = lane & 15;
  const int srow = t >> 1, shalf = t & 1;

  f32x4 acc[4][4];
  #pragma unroll
  for (int i = 0; i < 4; ++i)
    #pragma unroll
    for (int j = 0; j < 4; ++j) acc[i][j] = (f32x4){0.f, 0.f, 0.f, 0.f};

  const float* gA = X + (size_t)(m0 + srow) * 512 + shalf * 16;
  const float* gB = W + (size_t)(n0 + srow) * 512 + shalf * 16;
  const int wbyte = srow * 64;
  const int sw = (srow & 3) << 4;       // 64B rows -> 4 chunk slots -> 2-bit XOR swizzle

  #pragma unroll 1
  for (int kt = 0; kt < 16; ++kt) {
    float4 fa[4], fb[4];
    #pragma unroll
    for (int j = 0; j < 4; ++j) {
      fa[j] = *(const float4*)(gA + kt * 32 + j * 4);
      fb[j] = *(const float4*)(gB + kt * 32 + j * 4);
    }
    __syncthreads();                    // prev compute done before overwrite
    const float* pfa = (const float*)fa;
    const float* pfb = (const float*)fb;
    s16x8 va[2], vb[2];
    #pragma unroll
    for (int half = 0; half < 2; ++half)
      #pragma unroll
      for (int e = 0; e < 8; ++e) {
        va[half][e] = (short)f2bf(pfa[half * 8 + e]);
        vb[half][e] = (short)f2bf(pfb[half * 8 + e]);
      }
    #pragma unroll
    for (int half = 0; half < 2; ++half) {
      *(s16x8*)(lds_a + wbyte + ((shalf * 32 + half * 16) ^ sw)) = va[half];
      *(s16x8*)(lds_b + wbyte + ((shalf * 32 + half * 16) ^ sw)) = vb[half];
    }
    __syncthreads();
    s16x8 afr[4], bfr[4];
    #pragma unroll
    for (int mi = 0; mi < 4; ++mi) {
      int row = wr * 64 + mi * 16 + q15;
      afr[mi] = *(const s16x8*)(lds_a + row * 64 + ((g * 16) ^ ((row & 3) << 4)));
    }
    #pragma unroll
    for (int ni = 0; ni < 4; ++ni) {
      int row = wc * 64 + ni * 16 + q15;
      bfr[ni] = *(const s16x8*)(lds_b + row * 64 + ((g * 16) ^ ((row & 3) << 4)));
    }
    #pragma unroll
    for (int mi = 0; mi < 4; ++mi)
      #pragma unroll
      for (int ni = 0; ni < 4; ++ni)
        acc[mi][ni] = mfma_bf16(afr[mi], bfr[ni], acc[mi][ni]);
  }

  float bias[4];
  #pragma unroll
  for (int ni = 0; ni < 4; ++ni) bias[ni] = Bv[n0 + wc * 64 + ni * 16 + q15];

  if (z < 2) {
    u16* Out = z ? Ko : Qo;
    const float scale = z ? 1.0f : 0.125f;   // fold 1/sqrt(64) into Q (exact pow2)
    #pragma unroll
    for (int mi = 0; mi < 4; ++mi)
      #pragma unroll
      for (int ni = 0; ni < 4; ++ni)
        #pragma unroll
        for (int r = 0; r < 4; ++r) {
          int m = m0 + wr * 64 + mi * 16 + g * 4 + r;
          int n = n0 + wc * 64 + ni * 16 + q15;
          Out[(size_t)m * 512 + n] = f2bf((acc[mi][ni][r] + bias[ni]) * scale);
        }
  } else {
    __syncthreads();                    // all frag reads done; reuse smem
    #pragma unroll
    for (int mi = 0; mi < 4; ++mi)
      #pragma unroll
      for (int ni = 0; ni < 4; ++ni)
        #pragma unroll
        for (int r = 0; r < 4; ++r) {
          int ml = wr * 64 + mi * 16 + g * 4 + r;
          int nl = wc * 64 + ni * 16 + q15;
          *(u16*)(smem + nl * 272 + ml * 2) = f2bf(acc[mi][ni][r] + bias[ni]);
        }
    __syncthreads();
    const int b  = m0 >> 11;
    const int s0 = m0 & 2047;
    #pragma unroll
    for (int nn = 0; nn < 2; ++nn) {
      int n  = nn * 64 + (t >> 2);
      int q4 = t & 3;
      u16* dst = VTo + (size_t)(b * 512 + n0 + n) * 2048 + s0 + q4 * 32;
      #pragma unroll
      for (int jj = 0; jj < 4; ++jj)
        *(s16x8*)(dst + jj * 8) = *(const s16x8*)(smem + n * 272 + q4 * 64 + jj * 16);
    }
  }
}

// ---------------------------------------------------------------------------
// Kernel 2: fused flash attention.  grid.x = h + 8*b + 64*qt  (h fastest for
// mask L2/L3 reuse across the 8 heads), block 256 = 4 waves x 32 q-rows.
// ---------------------------------------------------------------------------
__global__ __launch_bounds__(256, 2)
void attn_fwd(const u16* __restrict__ Q, const u16* __restrict__ K,
              const u16* __restrict__ VT, const int* __restrict__ mask,
              float* __restrict__ out)
{
  __shared__ char lds_k[64 * 128];      // [kv][d] bf16, chunk-swizzled
  __shared__ char lds_v[64 * 128];      // [d][kv] bf16, chunk-swizzled
  __shared__ char lds_m[128 * 72];      // mask chars [q][kv], stride 72

  const int bid = blockIdx.x;
  const int h = bid & 7, b = (bid >> 3) & 7, qt = bid >> 6;
  const int t = threadIdx.x, lane = t & 63, w = t >> 6;
  const int g = lane >> 4, q15 = lane & 15;
  const int qbase = qt * 128 + w * 32;

  // Q fragments (pre-scaled by 1/8): B-operand of S^T = mfma(K, Q)
  s16x8 qf[2][2];
  #pragma unroll
  for (int qi = 0; qi < 2; ++qi)
    #pragma unroll
    for (int s = 0; s < 2; ++s)
      qf[qi][s] = *(const s16x8*)(Q + (size_t)(b * 2048 + qbase + qi * 16 + q15) * 512
                                    + h * 64 + s * 32 + g * 8);

  f32x4 o[2][4];
  #pragma unroll
  for (int qi = 0; qi < 2; ++qi)
    #pragma unroll
    for (int df = 0; df < 4; ++df) o[qi][df] = (f32x4){0.f, 0.f, 0.f, 0.f};
  float mrun[2] = {-INFINITY, -INFINITY};
  float lrun[2] = {0.f, 0.f};

  const int srow8 = lane >> 3, slot = lane & 7;
  const int mrow = t >> 1, mhalf = t & 1;
  const int* gM = mask + ((size_t)b * 2048 + qt * 128 + mrow) * 2048 + mhalf * 32;

  #pragma unroll 1
  for (int kt = 0; kt < 32; ++kt) {
    const int kv0 = kt * 64;
    i32x4 mv[8];
    #pragma unroll
    for (int jj = 0; jj < 8; ++jj) mv[jj] = *(const i32x4*)(gM + kv0 + jj * 4);
    // K / VT tiles -> LDS via direct-to-LDS, source pre-swizzled (linear dest)
    #pragma unroll
    for (int i = 0; i < 2; ++i) {
      int rl = w * 16 + i * 8 + srow8;
      gload_lds16(K  + (size_t)(b * 2048 + kv0 + rl) * 512 + h * 64 + ((slot ^ (rl & 7)) * 8),
                  lds_k + w * 2048 + i * 1024);
      gload_lds16(VT + (size_t)(b * 512 + h * 64 + rl) * 2048 + kv0 + ((slot ^ (rl & 7)) * 8),
                  lds_v + w * 2048 + i * 1024);
    }
    #pragma unroll
    for (int jj = 0; jj < 4; ++jj) {
      u32 lo = (mv[2*jj][0]   ? 1u : 0u) | (mv[2*jj][1]   ? 0x100u : 0u)
             | (mv[2*jj][2]   ? 0x10000u : 0u) | (mv[2*jj][3]   ? 0x1000000u : 0u);
      u32 hi = (mv[2*jj+1][0] ? 1u : 0u) | (mv[2*jj+1][1] ? 0x100u : 0u)
             | (mv[2*jj+1][2] ? 0x10000u : 0u) | (mv[2*jj+1][3] ? 0x1000000u : 0u);
      *(u64*)(lds_m + mrow * 72 + mhalf * 32 + jj * 8) = (u64)lo | ((u64)hi << 32);
    }
    __syncthreads();

    // S^T = mfma(K, Q): lane q15 owns q-row, kv = f*16 + 4g + r
    f32x4 p[2][4];
    #pragma unroll
    for (int qi = 0; qi < 2; ++qi)
      #pragma unroll
      for (int f = 0; f < 4; ++f) p[qi][f] = (f32x4){0.f, 0.f, 0.f, 0.f};
    #pragma unroll
    for (int s = 0; s < 2; ++s) {
      s16x8 kf[4];
      #pragma unroll
      for (int f = 0; f < 4; ++f) {
        int kvr = f * 16 + q15;
        kf[f] = *(const s16x8*)(lds_k + kvr * 128 + ((s * 64 + g * 16) ^ ((kvr & 7) << 4)));
      }
      #pragma unroll
      for (int qi = 0; qi < 2; ++qi)
        #pragma unroll
        for (int f = 0; f < 4; ++f)
          p[qi][f] = mfma_bf16(kf[f], qf[qi][s], p[qi][f]);
    }

    s16x8 pa[2][2];
    #pragma unroll
    for (int qi = 0; qi < 2; ++qi) {
      const int qrow = w * 32 + qi * 16 + q15;
      float tmax = -INFINITY;
      #pragma unroll
      for (int f = 0; f < 4; ++f)
        #pragma unroll
        for (int r = 0; r < 4; ++r) {
          char mc = lds_m[qrow * 72 + f * 16 + g * 4 + r];
          float sv = mc ? -1e9f : p[qi][f][r];
          p[qi][f][r] = sv;
          tmax = fmaxf(tmax, sv);
        }
      tmax = fmaxf(tmax, __shfl_xor(tmax, 16));
      tmax = fmaxf(tmax, __shfl_xor(tmax, 32));
      const float mnew  = fmaxf(mrun[qi], tmax);
      const float alpha = __expf(mrun[qi] - mnew);
      mrun[qi] = mnew;
      float lsum = 0.f;
      #pragma unroll
      for (int f = 0; f < 4; ++f)
        #pragma unroll
        for (int r = 0; r < 4; ++r) {
          float e = __expf(p[qi][f][r] - mnew);
          p[qi][f][r] = e;
          lsum += e;
        }
      lsum += __shfl_xor(lsum, 16);
      lsum += __shfl_xor(lsum, 32);
      lrun[qi] = lrun[qi] * alpha + lsum;

      // O-rescale: o[qi][df][r] holds q-row (g*4+r), NOT this lane's softmax
      // row (q15).  Fetch that row's alpha from the lane that owns it
      // (lane g*4+r has q15' == g*4+r; alpha is uniform across its 4 g's).
      float ar[4];
      #pragma unroll
      for (int r = 0; r < 4; ++r) ar[r] = __shfl(alpha, g * 4 + r);
      #pragma unroll
      for (int df = 0; df < 4; ++df)
        #pragma unroll
        for (int r = 0; r < 4; ++r) o[qi][df][r] *= ar[r];

      // P (exp'd, S^T layout) -> PV A-frag layout: pack frag-pair into u32,
      // one shfl moves both halves, receiver picks by lane>=32 (f' = 2s+(l>>5)).
      u32 wpk[2][4];
      #pragma unroll
      for (int s = 0; s < 2; ++s)
        #pragma unroll
        for (int r = 0; r < 4; ++r)
          wpk[s][r] = (u32)f2bf(p[qi][2*s][r]) | ((u32)f2bf(p[qi][2*s+1][r]) << 16);
      #pragma unroll
      for (int s = 0; s < 2; ++s) {
        s16x8 v;
        #pragma unroll
        for (int e = 0; e < 8; ++e) {
          int src = q15 + (((g & 1) * 2 + (e >> 2)) << 4);
          u32 word = (u32)__shfl((int)wpk[s][e & 3], src);
          v[e] = (short)(u16)((lane >= 32) ? (word >> 16) : (word & 0xffffu));
        }
        pa[qi][s] = v;
      }
    }

    // O += P * V
    #pragma unroll
    for (int s = 0; s < 2; ++s) {
      s16x8 vf[4];
      #pragma unroll
      for (int df = 0; df < 4; ++df) {
        int dr = df * 16 + q15;
        vf[df] = *(const s16x8*)(lds_v + dr * 128 + ((s * 64 + g * 16) ^ ((dr & 7) << 4)));
      }
      #pragma unroll
      for (int qi = 0; qi < 2; ++qi)
        #pragma unroll
        for (int df = 0; df < 4; ++df)
          o[qi][df] = mfma_bf16(pa[qi][s], vf[df], o[qi][df]);
    }
    __syncthreads();
  }

  #pragma unroll
  for (int qi = 0; qi < 2; ++qi)
    #pragma unroll
    for (int r = 0; r < 4; ++r) {
      float lv = __shfl(lrun[qi], g * 4 + r);   // row stats live at lanes 0..15
      float linv = 1.0f / lv;
      int qg = qbase + qi * 16 + g * 4 + r;
      float* po = out + (size_t)(b * 2048 + qg) * 512 + h * 64 + q15;
      #pragma unroll
      for (int df = 0; df < 4; ++df) po[df * 16] = o[qi][df][r] * linv;
    }
}

extern "C" void kernel_launch(void* const* d_in, const int* in_sizes, int n_in,
                              void* d_out, int out_size, void* d_ws, size_t ws_size,
                              hipStream_t stream) {
  const float* xq  = (const float*)d_in[0];
  const float* xkv = (const float*)d_in[1];
  const int*   msk = (const int*)d_in[2];
  const float* wq  = (const float*)d_in[3];
  const float* bq  = (const float*)d_in[4];
  const float* wk  = (const float*)d_in[5];
  const float* bk  = (const float*)d_in[6];
  const float* wv  = (const float*)d_in[7];
  const float* bv  = (const float*)d_in[8];

  u16* Qw = (u16*)d_ws;                          // [16384][512] bf16 (x 1/8)
  u16* Kw = Qw + (size_t)16384 * 512;            // [16384][512] bf16
  u16* VT = Kw + (size_t)16384 * 512;            // [4096][2048] bf16 (V^T)

  qkv_proj<<<dim3(128, 4, 3), 256, 0, stream>>>(xq, xkv, wq, bq, wk, bk, wv, bv,
                                                Qw, Kw, VT);
  attn_fwd<<<dim3(1024), 256, 0, stream>>>(Qw, Kw, VT, msk, (float*)d_out);
}

// Round 3
// 321.875 us; speedup vs baseline: 1.2521x; 1.2521x over previous
//
#include <hip/hip_runtime.h>
#include <hip/hip_bf16.h>
#include <math.h>

typedef float  f32x4 __attribute__((ext_vector_type(4)));
typedef short  s16x8 __attribute__((ext_vector_type(8)));
typedef __bf16 bf16x8 __attribute__((ext_vector_type(8)));
typedef unsigned int u32;
typedef unsigned short u16;
typedef unsigned long long u64;

#define DEVI static __device__ __forceinline__

DEVI u16 f2bf(float f) {
  u32 x = __builtin_bit_cast(u32, f);
  x += 0x7fffu + ((x >> 16) & 1u);   // RNE
  return (u16)(x >> 16);
}

DEVI f32x4 mfma_bf16(s16x8 a, s16x8 b, f32x4 c) {
  return __builtin_amdgcn_mfma_f32_16x16x32_bf16(
      __builtin_bit_cast(bf16x8, a), __builtin_bit_cast(bf16x8, b), c, 0, 0, 0);
}

DEVI void gload_lds16(const void* g, void* l) {
  __builtin_amdgcn_global_load_lds(
      (const __attribute__((address_space(1))) void*)g,
      (__attribute__((address_space(3))) void*)l, 16, 0, 0);
}

// ---------------------------------------------------------------------------
// Kernel 0: bit-pack the attention mask.  int32[8][2048][2048] ->
// u64[8][32][2048]  (word (b,kt,q) = bits for kv in [kt*64, kt*64+64)).
// One wave packs one (b,q,kt) via ballot; coalesced 256B reads.
// ---------------------------------------------------------------------------
__global__ __launch_bounds__(256)
void mask_pack(const int* __restrict__ mask, u64* __restrict__ mp) {
  const int t = threadIdx.x, lane = t & 63;
  const int gw = blockIdx.x * 4 + (t >> 6);
  const int kt = gw & 31, q = (gw >> 5) & 2047, b = gw >> 16;
  int mv = mask[((size_t)b * 2048 + q) * 2048 + kt * 64 + lane];
  u64 bits = __ballot(mv != 0);
  if (lane == 0) mp[((size_t)b * 32 + kt) * 2048 + q] = bits;
}

// ---------------------------------------------------------------------------
// Kernel 1: QKV projections.  z=0: Q=xq*wq^T+bq (scaled 1/8*log2e, bf16)
//           z=1: K           z=2: V written transposed as VT[b*512+h*64+d][s]
// grid (128, 4, 3), block 256.
// ---------------------------------------------------------------------------
__global__ __launch_bounds__(256, 2)
void qkv_proj(const float* __restrict__ xq, const float* __restrict__ xkv,
              const float* __restrict__ wq, const float* __restrict__ bq,
              const float* __restrict__ wk, const float* __restrict__ bk,
              const float* __restrict__ wv, const float* __restrict__ bv,
              u16* __restrict__ Qo, u16* __restrict__ Ko, u16* __restrict__ VTo)
{
  __shared__ char smem[128 * 272];      // staging A[0,8K) B[8K,16K); V-transpose buf
  char* lds_a = smem;
  char* lds_b = smem + 8192;

  const int z = blockIdx.z;
  const float* X  = (z == 0) ? xq : xkv;
  const float* W  = (z == 0) ? wq : (z == 1 ? wk : wv);
  const float* Bv = (z == 0) ? bq : (z == 1 ? bk : bv);

  const int m0 = blockIdx.x * 128, n0 = blockIdx.y * 128;
  const int t = threadIdx.x, lane = t & 63, w = t >> 6;
  const int wr = w >> 1, wc = w & 1, g = lane >> 4, q15 = lane & 15;
  const int srow = t >> 1, shalf = t & 1;

  f32x4 acc[4][4];
  #pragma unroll
  for (int i = 0; i < 4; ++i)
    #pragma unroll
    for (int j = 0; j < 4; ++j) acc[i][j] = (f32x4){0.f, 0.f, 0.f, 0.f};

  const float* gA = X + (size_t)(m0 + srow) * 512 + shalf * 16;
  const float* gB = W + (size_t)(n0 + srow) * 512 + shalf * 16;
  const int wbyte = srow * 64;
  const int sw = (srow & 3) << 4;

  #pragma unroll 1
  for (int kt = 0; kt < 16; ++kt) {
    float4 fa[4], fb[4];
    #pragma unroll
    for (int j = 0; j < 4; ++j) {
      fa[j] = *(const float4*)(gA + kt * 32 + j * 4);
      fb[j] = *(const float4*)(gB + kt * 32 + j * 4);
    }
    __syncthreads();                    // prev compute done before overwrite
    const float* pfa = (const float*)fa;
    const float* pfb = (const float*)fb;
    s16x8 va[2], vb[2];
    #pragma unroll
    for (int half = 0; half < 2; ++half)
      #pragma unroll
      for (int e = 0; e < 8; ++e) {
        va[half][e] = (short)f2bf(pfa[half * 8 + e]);
        vb[half][e] = (short)f2bf(pfb[half * 8 + e]);
      }
    #pragma unroll
    for (int half = 0; half < 2; ++half) {
      *(s16x8*)(lds_a + wbyte + ((shalf * 32 + half * 16) ^ sw)) = va[half];
      *(s16x8*)(lds_b + wbyte + ((shalf * 32 + half * 16) ^ sw)) = vb[half];
    }
    __syncthreads();
    s16x8 afr[4], bfr[4];
    #pragma unroll
    for (int mi = 0; mi < 4; ++mi) {
      int row = wr * 64 + mi * 16 + q15;
      afr[mi] = *(const s16x8*)(lds_a + row * 64 + ((g * 16) ^ ((row & 3) << 4)));
    }
    #pragma unroll
    for (int ni = 0; ni < 4; ++ni) {
      int row = wc * 64 + ni * 16 + q15;
      bfr[ni] = *(const s16x8*)(lds_b + row * 64 + ((g * 16) ^ ((row & 3) << 4)));
    }
    #pragma unroll
    for (int mi = 0; mi < 4; ++mi)
      #pragma unroll
      for (int ni = 0; ni < 4; ++ni)
        acc[mi][ni] = mfma_bf16(afr[mi], bfr[ni], acc[mi][ni]);
  }

  float bias[4];
  #pragma unroll
  for (int ni = 0; ni < 4; ++ni) bias[ni] = Bv[n0 + wc * 64 + ni * 16 + q15];

  if (z < 2) {
    u16* Out = z ? Ko : Qo;
    // Q: fold 1/sqrt(64) * log2(e) so attention works in exp2 domain
    const float scale = z ? 1.0f : 0.18033688011112042f;
    #pragma unroll
    for (int mi = 0; mi < 4; ++mi)
      #pragma unroll
      for (int ni = 0; ni < 4; ++ni)
        #pragma unroll
        for (int r = 0; r < 4; ++r) {
          int m = m0 + wr * 64 + mi * 16 + g * 4 + r;
          int n = n0 + wc * 64 + ni * 16 + q15;
          Out[(size_t)m * 512 + n] = f2bf((acc[mi][ni][r] + bias[ni]) * scale);
        }
  } else {
    __syncthreads();                    // all frag reads done; reuse smem
    #pragma unroll
    for (int mi = 0; mi < 4; ++mi)
      #pragma unroll
      for (int ni = 0; ni < 4; ++ni)
        #pragma unroll
        for (int r = 0; r < 4; ++r) {
          int ml = wr * 64 + mi * 16 + g * 4 + r;
          int nl = wc * 64 + ni * 16 + q15;
          *(u16*)(smem + nl * 272 + ml * 2) = f2bf(acc[mi][ni][r] + bias[ni]);
        }
    __syncthreads();
    const int b  = m0 >> 11;
    const int s0 = m0 & 2047;
    #pragma unroll
    for (int nn = 0; nn < 2; ++nn) {
      int n  = nn * 64 + (t >> 2);
      int q4 = t & 3;
      u16* dst = VTo + (size_t)(b * 512 + n0 + n) * 2048 + s0 + q4 * 32;
      #pragma unroll
      for (int jj = 0; jj < 4; ++jj)
        *(s16x8*)(dst + jj * 8) = *(const s16x8*)(smem + n * 272 + q4 * 64 + jj * 16);
    }
  }
}

// ---------------------------------------------------------------------------
// Kernel 2: fused flash attention, double-buffered K/V with counted vmcnt.
// grid.x = h + 8*b + 64*qt; block 256 = 4 waves x 32 q-rows.
// ---------------------------------------------------------------------------
__global__ __launch_bounds__(256, 2)
void attn_fwd(const u16* __restrict__ Q, const u16* __restrict__ K,
              const u16* __restrict__ VT, const u64* __restrict__ MP,
              float* __restrict__ out)
{
  __shared__ char lds_k[2][8192];       // [kv][d] bf16, chunk-swizzled
  __shared__ char lds_v[2][8192];       // [d][kv] bf16, chunk-swizzled

  const int bid = blockIdx.x;
  const int h = bid & 7, b = (bid >> 3) & 7, qt = bid >> 6;
  const int t = threadIdx.x, lane = t & 63, w = t >> 6;
  const int g = lane >> 4, q15 = lane & 15;
  const int qbase = qt * 128 + w * 32;

  // Q fragments (pre-scaled by 0.125*log2e): B-operand of S^T = mfma(K, Q)
  s16x8 qf[2][2];
  #pragma unroll
  for (int qi = 0; qi < 2; ++qi)
    #pragma unroll
    for (int s = 0; s < 2; ++s)
      qf[qi][s] = *(const s16x8*)(Q + (size_t)(b * 2048 + qbase + qi * 16 + q15) * 512
                                    + h * 64 + s * 32 + g * 8);
  asm volatile("" ::: "memory");        // pin qf loads before STAGE(0)

  f32x4 o[2][4];
  #pragma unroll
  for (int qi = 0; qi < 2; ++qi)
    #pragma unroll
    for (int df = 0; df < 4; ++df) o[qi][df] = (f32x4){0.f, 0.f, 0.f, 0.f};
  float mrun[2] = {-INFINITY, -INFINITY};
  float lrun[2] = {0.f, 0.f};

  const int srow8 = lane >> 3, slot = lane & 7;
  const u64* MPb = MP + (size_t)b * 32 * 2048;
  const int qrow0 = qbase + q15, qrow1 = qbase + 16 + q15;

#define STAGE(kt_, buf_) do {                                                  \
    const int kv0_ = (kt_) * 64;                                               \
    _Pragma("unroll")                                                          \
    for (int i_ = 0; i_ < 2; ++i_) {                                           \
      int rl_ = w * 16 + i_ * 8 + srow8;                                       \
      gload_lds16(K + (size_t)(b * 2048 + kv0_ + rl_) * 512 + h * 64           \
                      + ((slot ^ (rl_ & 7)) * 8),                              \
                  &lds_k[buf_][w * 2048 + i_ * 1024]);                         \
      gload_lds16(VT + (size_t)(b * 512 + h * 64 + rl_) * 2048 + kv0_         \
                      + ((slot ^ (rl_ & 7)) * 8),                              \
                  &lds_v[buf_][w * 2048 + i_ * 1024]);                         \
    } } while (0)

  STAGE(0, 0);
  asm volatile("" ::: "memory");        // stage(0) issued before mask prefetch
  u64 pm0 = MPb[qrow0], pm1 = MPb[qrow1];

  #pragma unroll 1
  for (int kt = 0; kt < 32; ++kt) {
    const int cur = kt & 1;
    const u64 mw[2] = {pm0, pm1};
    if (kt + 1 < 32) {
      STAGE(kt + 1, cur ^ 1);
      asm volatile("" ::: "memory");    // stage before mask prefetch (order for vmcnt count)
      pm0 = MPb[(kt + 1) * 2048 + qrow0];
      pm1 = MPb[(kt + 1) * 2048 + qrow1];
      // outstanding after stage(kt): mask(kt)=2 + stage(kt+1)=4 + mask(kt+1)=2 = 8
      asm volatile("s_waitcnt vmcnt(8)" ::: "memory");
    } else {
      // only mask(31)=2 newer than stage(31)
      asm volatile("s_waitcnt vmcnt(2)" ::: "memory");
    }
    asm volatile("s_barrier" ::: "memory");

    // S^T = mfma(K, Q): lane q15 owns q-row, kv = f*16 + 4g + r
    f32x4 p[2][4];
    #pragma unroll
    for (int qi = 0; qi < 2; ++qi)
      #pragma unroll
      for (int f = 0; f < 4; ++f) p[qi][f] = (f32x4){0.f, 0.f, 0.f, 0.f};
    #pragma unroll
    for (int s = 0; s < 2; ++s) {
      s16x8 kf[4];
      #pragma unroll
      for (int f = 0; f < 4; ++f) {
        int kvr = f * 16 + q15;
        kf[f] = *(const s16x8*)(&lds_k[cur][kvr * 128 + ((s * 64 + g * 16) ^ ((kvr & 7) << 4))]);
      }
      #pragma unroll
      for (int qi = 0; qi < 2; ++qi)
        #pragma unroll
        for (int f = 0; f < 4; ++f)
          p[qi][f] = mfma_bf16(kf[f], qf[qi][s], p[qi][f]);
    }

    s16x8 pa[2][2];
    #pragma unroll
    for (int qi = 0; qi < 2; ++qi) {
      const u32 mlo = (u32)mw[qi], mhi = (u32)(mw[qi] >> 32);
      float tmax = -INFINITY;
      #pragma unroll
      for (int f = 0; f < 4; ++f) {
        u32 nib = ((f < 2 ? mlo : mhi) >> (((f & 1) << 4) + g * 4)) & 0xFu;
        #pragma unroll
        for (int r = 0; r < 4; ++r) {
          float sv = ((nib >> r) & 1u) ? -1e9f : p[qi][f][r];
          p[qi][f][r] = sv;
          tmax = fmaxf(tmax, sv);
        }
      }
      tmax = fmaxf(tmax, __shfl_xor(tmax, 16));
      tmax = fmaxf(tmax, __shfl_xor(tmax, 32));
      const float mnew  = fmaxf(mrun[qi], tmax);
      const float alpha = exp2f(mrun[qi] - mnew);
      mrun[qi] = mnew;
      float lsum = 0.f;
      #pragma unroll
      for (int f = 0; f < 4; ++f)
        #pragma unroll
        for (int r = 0; r < 4; ++r) {
          float e = exp2f(p[qi][f][r] - mnew);
          p[qi][f][r] = e;
          lsum += e;
        }
      lsum += __shfl_xor(lsum, 16);
      lsum += __shfl_xor(lsum, 32);
      lrun[qi] = lrun[qi] * alpha + lsum;

      // O-rescale: o[qi][df][r] holds q-row (g*4+r) -> need that row's alpha
      float ar[4];
      #pragma unroll
      for (int r = 0; r < 4; ++r) ar[r] = __shfl(alpha, g * 4 + r);
      #pragma unroll
      for (int df = 0; df < 4; ++df)
        #pragma unroll
        for (int r = 0; r < 4; ++r) o[qi][df][r] *= ar[r];

      // P (exp'd, S^T layout) -> PV A-frag layout via packed shfl
      u32 wpk[2][4];
      #pragma unroll
      for (int s = 0; s < 2; ++s)
        #pragma unroll
        for (int r = 0; r < 4; ++r)
          wpk[s][r] = (u32)f2bf(p[qi][2*s][r]) | ((u32)f2bf(p[qi][2*s+1][r]) << 16);
      #pragma unroll
      for (int s = 0; s < 2; ++s) {
        s16x8 v;
        #pragma unroll
        for (int e = 0; e < 8; ++e) {
          int src = q15 + (((g & 1) * 2 + (e >> 2)) << 4);
          u32 word = (u32)__shfl((int)wpk[s][e & 3], src);
          v[e] = (short)(u16)((lane >= 32) ? (word >> 16) : (word & 0xffffu));
        }
        pa[qi][s] = v;
      }
    }

    // O += P * V
    #pragma unroll
    for (int s = 0; s < 2; ++s) {
      s16x8 vf[4];
      #pragma unroll
      for (int df = 0; df < 4; ++df) {
        int dr = df * 16 + q15;
        vf[df] = *(const s16x8*)(&lds_v[cur][dr * 128 + ((s * 64 + g * 16) ^ ((dr & 7) << 4))]);
      }
      #pragma unroll
      for (int qi = 0; qi < 2; ++qi)
        #pragma unroll
        for (int df = 0; df < 4; ++df)
          o[qi][df] = mfma_bf16(pa[qi][s], vf[df], o[qi][df]);
    }

    asm volatile("s_waitcnt lgkmcnt(0)" ::: "memory");
    __builtin_amdgcn_sched_barrier(0);
    asm volatile("s_barrier" ::: "memory");   // reads done before next overwrite
  }

  #pragma unroll
  for (int qi = 0; qi < 2; ++qi)
    #pragma unroll
    for (int r = 0; r < 4; ++r) {
      float lv = __shfl(lrun[qi], g * 4 + r);   // row stats live at lanes 0..15
      float linv = 1.0f / lv;
      int qg = qbase + qi * 16 + g * 4 + r;
      float* po = out + (size_t)(b * 2048 + qg) * 512 + h * 64 + q15;
      #pragma unroll
      for (int df = 0; df < 4; ++df) po[df * 16] = o[qi][df][r] * linv;
    }
}

extern "C" void kernel_launch(void* const* d_in, const int* in_sizes, int n_in,
                              void* d_out, int out_size, void* d_ws, size_t ws_size,
                              hipStream_t stream) {
  const float* xq  = (const float*)d_in[0];
  const float* xkv = (const float*)d_in[1];
  const int*   msk = (const int*)d_in[2];
  const float* wq  = (const float*)d_in[3];
  const float* bq  = (const float*)d_in[4];
  const float* wk  = (const float*)d_in[5];
  const float* bk  = (const float*)d_in[6];
  const float* wv  = (const float*)d_in[7];
  const float* bv  = (const float*)d_in[8];

  u16* Qw = (u16*)d_ws;                          // [16384][512] bf16 (x 0.1803)
  u16* Kw = Qw + (size_t)16384 * 512;            // [16384][512] bf16
  u16* VT = Kw + (size_t)16384 * 512;            // [4096][2048] bf16 (V^T)
  u64* MP = (u64*)(VT + (size_t)4096 * 2048);    // [8][32][2048] packed mask

  mask_pack<<<dim3(131072), 256, 0, stream>>>(msk, MP);
  qkv_proj<<<dim3(128, 4, 3), 256, 0, stream>>>(xq, xkv, wq, bq, wk, bk, wv, bv,
                                                Qw, Kw, VT);
  attn_fwd<<<dim3(1024), 256, 0, stream>>>(Qw, Kw, VT, MP, (float*)d_out);
}

// Round 4
// 287.579 us; speedup vs baseline: 1.4015x; 1.1193x over previous
//
#include <hip/hip_runtime.h>
#include <hip/hip_bf16.h>
#include <math.h>

typedef float  f32x4 __attribute__((ext_vector_type(4)));
typedef short  s16x8 __attribute__((ext_vector_type(8)));
typedef __bf16 bf16x8 __attribute__((ext_vector_type(8)));
typedef unsigned int u32;
typedef unsigned short u16;
typedef unsigned long long u64;

#define DEVI static __device__ __forceinline__

DEVI u16 f2bf(float f) {
  u32 x = __builtin_bit_cast(u32, f);
  x += 0x7fffu + ((x >> 16) & 1u);   // RNE
  return (u16)(x >> 16);
}

// packed bf16 pair via compiler casts (emits v_cvt_pk_bf16_f32)
DEVI u32 pk2bf(float lo, float hi) {
  u16 l = __builtin_bit_cast(u16, (__bf16)lo);
  u16 h = __builtin_bit_cast(u16, (__bf16)hi);
  return (u32)l | ((u32)h << 16);
}

DEVI f32x4 mfma_bf16(s16x8 a, s16x8 b, f32x4 c) {
  return __builtin_amdgcn_mfma_f32_16x16x32_bf16(
      __builtin_bit_cast(bf16x8, a), __builtin_bit_cast(bf16x8, b), c, 0, 0, 0);
}

DEVI void gload_lds16(const void* g, void* l) {
  __builtin_amdgcn_global_load_lds(
      (const __attribute__((address_space(1))) void*)g,
      (__attribute__((address_space(3))) void*)l, 16, 0, 0);
}

// ---------------------------------------------------------------------------
// Kernel 0: bit-pack KEEP bits.  int32[8][2048][2048] -> u64[8][32][2048]
// word (b,kt,q): bit l == 1  iff  kv = kt*64+l is KEPT (mask == 0).
// ---------------------------------------------------------------------------
__global__ __launch_bounds__(256)
void mask_pack(const int* __restrict__ mask, u64* __restrict__ mp) {
  const int t = threadIdx.x, lane = t & 63;
  const int gw = blockIdx.x * 4 + (t >> 6);
  const int kt = gw & 31, q = (gw >> 5) & 2047, b = gw >> 16;
  int mv = mask[((size_t)b * 2048 + q) * 2048 + kt * 64 + lane];
  u64 bits = __ballot(mv == 0);
  if (lane == 0) mp[((size_t)b * 32 + kt) * 2048 + q] = bits;
}

// ---------------------------------------------------------------------------
// Kernel 1: QKV projections.  z=0: Q=xq*wq^T+bq (scaled 1/8*log2e, bf16)
//           z=1: K           z=2: V written transposed as VT[b*512+h*64+d][s]
// ---------------------------------------------------------------------------
__global__ __launch_bounds__(256, 2)
void qkv_proj(const float* __restrict__ xq, const float* __restrict__ xkv,
              const float* __restrict__ wq, const float* __restrict__ bq,
              const float* __restrict__ wk, const float* __restrict__ bk,
              const float* __restrict__ wv, const float* __restrict__ bv,
              u16* __restrict__ Qo, u16* __restrict__ Ko, u16* __restrict__ VTo)
{
  __shared__ char smem[128 * 272];      // staging A[0,8K) B[8K,16K); V-transpose buf
  char* lds_a = smem;
  char* lds_b = smem + 8192;

  const int z = blockIdx.z;
  const float* X  = (z == 0) ? xq : xkv;
  const float* W  = (z == 0) ? wq : (z == 1 ? wk : wv);
  const float* Bv = (z == 0) ? bq : (z == 1 ? bk : bv);

  const int m0 = blockIdx.x * 128, n0 = blockIdx.y * 128;
  const int t = threadIdx.x, lane = t & 63, w = t >> 6;
  const int wr = w >> 1, wc = w & 1, g = lane >> 4, q15 = lane & 15;
  const int srow = t >> 1, shalf = t & 1;

  f32x4 acc[4][4];
  #pragma unroll
  for (int i = 0; i < 4; ++i)
    #pragma unroll
    for (int j = 0; j < 4; ++j) acc[i][j] = (f32x4){0.f, 0.f, 0.f, 0.f};

  const float* gA = X + (size_t)(m0 + srow) * 512 + shalf * 16;
  const float* gB = W + (size_t)(n0 + srow) * 512 + shalf * 16;
  const int wbyte = srow * 64;
  const int sw = (srow & 3) << 4;

  #pragma unroll 1
  for (int kt = 0; kt < 16; ++kt) {
    float4 fa[4], fb[4];
    #pragma unroll
    for (int j = 0; j < 4; ++j) {
      fa[j] = *(const float4*)(gA + kt * 32 + j * 4);
      fb[j] = *(const float4*)(gB + kt * 32 + j * 4);
    }
    __syncthreads();                    // prev compute done before overwrite
    const float* pfa = (const float*)fa;
    const float* pfb = (const float*)fb;
    s16x8 va[2], vb[2];
    #pragma unroll
    for (int half = 0; half < 2; ++half)
      #pragma unroll
      for (int e = 0; e < 8; ++e) {
        va[half][e] = (short)f2bf(pfa[half * 8 + e]);
        vb[half][e] = (short)f2bf(pfb[half * 8 + e]);
      }
    #pragma unroll
    for (int half = 0; half < 2; ++half) {
      *(s16x8*)(lds_a + wbyte + ((shalf * 32 + half * 16) ^ sw)) = va[half];
      *(s16x8*)(lds_b + wbyte + ((shalf * 32 + half * 16) ^ sw)) = vb[half];
    }
    __syncthreads();
    s16x8 afr[4], bfr[4];
    #pragma unroll
    for (int mi = 0; mi < 4; ++mi) {
      int row = wr * 64 + mi * 16 + q15;
      afr[mi] = *(const s16x8*)(lds_a + row * 64 + ((g * 16) ^ ((row & 3) << 4)));
    }
    #pragma unroll
    for (int ni = 0; ni < 4; ++ni) {
      int row = wc * 64 + ni * 16 + q15;
      bfr[ni] = *(const s16x8*)(lds_b + row * 64 + ((g * 16) ^ ((row & 3) << 4)));
    }
    #pragma unroll
    for (int mi = 0; mi < 4; ++mi)
      #pragma unroll
      for (int ni = 0; ni < 4; ++ni)
        acc[mi][ni] = mfma_bf16(afr[mi], bfr[ni], acc[mi][ni]);
  }

  float bias[4];
  #pragma unroll
  for (int ni = 0; ni < 4; ++ni) bias[ni] = Bv[n0 + wc * 64 + ni * 16 + q15];

  if (z < 2) {
    u16* Out = z ? Ko : Qo;
    // Q: fold 1/sqrt(64) * log2(e) so attention works in exp2 domain
    const float scale = z ? 1.0f : 0.18033688011112042f;
    #pragma unroll
    for (int mi = 0; mi < 4; ++mi)
      #pragma unroll
      for (int ni = 0; ni < 4; ++ni)
        #pragma unroll
        for (int r = 0; r < 4; ++r) {
          int m = m0 + wr * 64 + mi * 16 + g * 4 + r;
          int n = n0 + wc * 64 + ni * 16 + q15;
          Out[(size_t)m * 512 + n] = f2bf((acc[mi][ni][r] + bias[ni]) * scale);
        }
  } else {
    __syncthreads();                    // all frag reads done; reuse smem
    #pragma unroll
    for (int mi = 0; mi < 4; ++mi)
      #pragma unroll
      for (int ni = 0; ni < 4; ++ni)
        #pragma unroll
        for (int r = 0; r < 4; ++r) {
          int ml = wr * 64 + mi * 16 + g * 4 + r;
          int nl = wc * 64 + ni * 16 + q15;
          *(u16*)(smem + nl * 272 + ml * 2) = f2bf(acc[mi][ni][r] + bias[ni]);
        }
    __syncthreads();
    const int b  = m0 >> 11;
    const int s0 = m0 & 2047;
    #pragma unroll
    for (int nn = 0; nn < 2; ++nn) {
      int n  = nn * 64 + (t >> 2);
      int q4 = t & 3;
      u16* dst = VTo + (size_t)(b * 512 + n0 + n) * 2048 + s0 + q4 * 32;
      #pragma unroll
      for (int jj = 0; jj < 4; ++jj)
        *(s16x8*)(dst + jj * 8) = *(const s16x8*)(smem + n * 272 + q4 * 64 + jj * 16);
    }
  }
}

// ---------------------------------------------------------------------------
// Kernel 2: fused flash attention, no-max softmax (exp2 domain, safe since
// |Shat| <= ~15 << 127), keep-bit masking, double-buffered K/V, counted vmcnt.
// grid.x = h + 8*b + 64*qt; block 256 = 4 waves x 32 q-rows.
// ---------------------------------------------------------------------------
__global__ __launch_bounds__(256, 2)
void attn_fwd(const u16* __restrict__ Q, const u16* __restrict__ K,
              const u16* __restrict__ VT, const u64* __restrict__ MP,
              float* __restrict__ out)
{
  __shared__ char lds_k[2][8192];       // [kv][d] bf16, chunk-swizzled
  __shared__ char lds_v[2][8192];       // [d][kv] bf16, chunk-swizzled

  const int bid = blockIdx.x;
  const int h = bid & 7, b = (bid >> 3) & 7, qt = bid >> 6;
  const int t = threadIdx.x, lane = t & 63, w = t >> 6;
  const int g = lane >> 4, q15 = lane & 15;
  const int qbase = qt * 128 + w * 32;

  // Q fragments (pre-scaled by 0.125*log2e): B-operand of S^T = mfma(K, Q)
  s16x8 qf[2][2];
  #pragma unroll
  for (int qi = 0; qi < 2; ++qi)
    #pragma unroll
    for (int s = 0; s < 2; ++s)
      qf[qi][s] = *(const s16x8*)(Q + (size_t)(b * 2048 + qbase + qi * 16 + q15) * 512
                                    + h * 64 + s * 32 + g * 8);
  asm volatile("" ::: "memory");        // pin qf loads before STAGE(0)

  f32x4 o[2][4];
  #pragma unroll
  for (int qi = 0; qi < 2; ++qi)
    #pragma unroll
    for (int df = 0; df < 4; ++df) o[qi][df] = (f32x4){0.f, 0.f, 0.f, 0.f};
  float lrun[2] = {0.f, 0.f};           // per-lane partial sum of exp2 terms

  const int srow8 = lane >> 3, slot = lane & 7;
  const u64* MPb = MP + (size_t)b * 32 * 2048;
  const int qrow0 = qbase + q15, qrow1 = qbase + 16 + q15;

#define STAGE(kt_, buf_) do {                                                  \
    const int kv0_ = (kt_) * 64;                                               \
    _Pragma("unroll")                                                          \
    for (int i_ = 0; i_ < 2; ++i_) {                                           \
      int rl_ = w * 16 + i_ * 8 + srow8;                                       \
      gload_lds16(K + (size_t)(b * 2048 + kv0_ + rl_) * 512 + h * 64           \
                      + ((slot ^ (rl_ & 7)) * 8),                              \
                  &lds_k[buf_][w * 2048 + i_ * 1024]);                         \
      gload_lds16(VT + (size_t)(b * 512 + h * 64 + rl_) * 2048 + kv0_         \
                      + ((slot ^ (rl_ & 7)) * 8),                              \
                  &lds_v[buf_][w * 2048 + i_ * 1024]);                         \
    } } while (0)

  STAGE(0, 0);
  asm volatile("" ::: "memory");        // stage(0) issued before mask prefetch
  u64 pm0 = MPb[qrow0], pm1 = MPb[qrow1];

  #pragma unroll 1
  for (int kt = 0; kt < 32; ++kt) {
    const int cur = kt & 1;
    const u64 mw[2] = {pm0, pm1};
    if (kt + 1 < 32) {
      STAGE(kt + 1, cur ^ 1);
      asm volatile("" ::: "memory");    // stage before mask prefetch (order for vmcnt count)
      pm0 = MPb[(kt + 1) * 2048 + qrow0];
      pm1 = MPb[(kt + 1) * 2048 + qrow1];
      // outstanding after stage(kt): mask(kt)=2 + stage(kt+1)=4 + mask(kt+1)=2 = 8
      asm volatile("s_waitcnt vmcnt(8)" ::: "memory");
    } else {
      // only mask(31)=2 newer than stage(31)
      asm volatile("s_waitcnt vmcnt(2)" ::: "memory");
    }
    asm volatile("s_barrier" ::: "memory");

    // S^T = mfma(K, Q): lane q15 owns q-row, kv = f*16 + 4g + r
    f32x4 p[2][4];
    #pragma unroll
    for (int qi = 0; qi < 2; ++qi)
      #pragma unroll
      for (int f = 0; f < 4; ++f) p[qi][f] = (f32x4){0.f, 0.f, 0.f, 0.f};
    #pragma unroll
    for (int s = 0; s < 2; ++s) {
      s16x8 kf[4];
      #pragma unroll
      for (int f = 0; f < 4; ++f) {
        int kvr = f * 16 + q15;
        kf[f] = *(const s16x8*)(&lds_k[cur][kvr * 128 + ((s * 64 + g * 16) ^ ((kvr & 7) << 4))]);
      }
      #pragma unroll
      for (int qi = 0; qi < 2; ++qi)
        #pragma unroll
        for (int f = 0; f < 4; ++f)
          p[qi][f] = mfma_bf16(kf[f], qf[qi][s], p[qi][f]);
    }

    s16x8 pa[2][2];
    #pragma unroll
    for (int qi = 0; qi < 2; ++qi) {
      const u32 klo = (u32)mw[qi], khi = (u32)(mw[qi] >> 32);  // keep bits
      float lsum = 0.f;
      #pragma unroll
      for (int f = 0; f < 4; ++f) {
        const u32 kw = (f < 2) ? klo : khi;
        const int boff = ((f & 1) << 4) + g * 4;
        #pragma unroll
        for (int r = 0; r < 4; ++r) {
          // keep = all-ones iff bit set (v_bfe_i32 pattern), AND after exp2
          u32 keep = (u32)((int)(kw << (31 - boff - r)) >> 31);
          float ev = exp2f(p[qi][f][r]);
          ev = __builtin_bit_cast(float, __builtin_bit_cast(u32, ev) & keep);
          p[qi][f][r] = ev;
          lsum += ev;
        }
      }
      lrun[qi] += lsum;                 // cross-lane reduce deferred to end

      // P (exp'd, S^T layout) -> PV A-frag layout via packed shfl
      u32 wpk[2][4];
      #pragma unroll
      for (int s = 0; s < 2; ++s)
        #pragma unroll
        for (int r = 0; r < 4; ++r)
          wpk[s][r] = pk2bf(p[qi][2*s][r], p[qi][2*s+1][r]);
      #pragma unroll
      for (int s = 0; s < 2; ++s) {
        s16x8 v;
        #pragma unroll
        for (int e = 0; e < 8; ++e) {
          int src = q15 + (((g & 1) * 2 + (e >> 2)) << 4);
          u32 word = (u32)__shfl((int)wpk[s][e & 3], src);
          v[e] = (short)(u16)((lane >= 32) ? (word >> 16) : (word & 0xffffu));
        }
        pa[qi][s] = v;
      }
    }

    // O += P * V
    #pragma unroll
    for (int s = 0; s < 2; ++s) {
      s16x8 vf[4];
      #pragma unroll
      for (int df = 0; df < 4; ++df) {
        int dr = df * 16 + q15;
        vf[df] = *(const s16x8*)(&lds_v[cur][dr * 128 + ((s * 64 + g * 16) ^ ((dr & 7) << 4))]);
      }
      #pragma unroll
      for (int qi = 0; qi < 2; ++qi)
        #pragma unroll
        for (int df = 0; df < 4; ++df)
          o[qi][df] = mfma_bf16(pa[qi][s], vf[df], o[qi][df]);
    }

    asm volatile("s_waitcnt lgkmcnt(0)" ::: "memory");
    __builtin_amdgcn_sched_barrier(0);
    asm volatile("s_barrier" ::: "memory");   // reads done before next overwrite
  }

  // full row sums: lanes with same q15 across the 4 g-groups hold disjoint kv
  #pragma unroll
  for (int qi = 0; qi < 2; ++qi) {
    lrun[qi] += __shfl_xor(lrun[qi], 16);
    lrun[qi] += __shfl_xor(lrun[qi], 32);
  }

  #pragma unroll
  for (int qi = 0; qi < 2; ++qi)
    #pragma unroll
    for (int r = 0; r < 4; ++r) {
      float lv = __shfl(lrun[qi], g * 4 + r);   // row stats live at lanes 0..15
      float linv = 1.0f / lv;
      int qg = qbase + qi * 16 + g * 4 + r;
      float* po = out + (size_t)(b * 2048 + qg) * 512 + h * 64 + q15;
      #pragma unroll
      for (int df = 0; df < 4; ++df) po[df * 16] = o[qi][df][r] * linv;
    }
}

extern "C" void kernel_launch(void* const* d_in, const int* in_sizes, int n_in,
                              void* d_out, int out_size, void* d_ws, size_t ws_size,
                              hipStream_t stream) {
  const float* xq  = (const float*)d_in[0];
  const float* xkv = (const float*)d_in[1];
  const int*   msk = (const int*)d_in[2];
  const float* wq  = (const float*)d_in[3];
  const float* bq  = (const float*)d_in[4];
  const float* wk  = (const float*)d_in[5];
  const float* bk  = (const float*)d_in[6];
  const float* wv  = (const float*)d_in[7];
  const float* bv  = (const float*)d_in[8];

  u16* Qw = (u16*)d_ws;                          // [16384][512] bf16 (x 0.1803)
  u16* Kw = Qw + (size_t)16384 * 512;            // [16384][512] bf16
  u16* VT = Kw + (size_t)16384 * 512;            // [4096][2048] bf16 (V^T)
  u64* MP = (u64*)(VT + (size_t)4096 * 2048);    // [8][32][2048] packed keep bits

  mask_pack<<<dim3(131072), 256, 0, stream>>>(msk, MP);
  qkv_proj<<<dim3(128, 4, 3), 256, 0, stream>>>(xq, xkv, wq, bq, wk, bk, wv, bv,
                                                Qw, Kw, VT);
  attn_fwd<<<dim3(1024), 256, 0, stream>>>(Qw, Kw, VT, MP, (float*)d_out);
}

// Round 5
// 263.395 us; speedup vs baseline: 1.5302x; 1.0918x over previous
//
#include <hip/hip_runtime.h>
#include <hip/hip_bf16.h>
#include <math.h>

typedef float  f32x4  __attribute__((ext_vector_type(4)));
typedef float  f32x16 __attribute__((ext_vector_type(16)));
typedef short  s16x8  __attribute__((ext_vector_type(8)));
typedef __bf16 bf16x8 __attribute__((ext_vector_type(8)));
typedef unsigned int u32;
typedef unsigned int u32x4 __attribute__((ext_vector_type(4)));
typedef unsigned short u16;
typedef unsigned long long u64;

#define DEVI static __device__ __forceinline__

DEVI u16 f2bf(float f) {
  u32 x = __builtin_bit_cast(u32, f);
  x += 0x7fffu + ((x >> 16) & 1u);   // RNE
  return (u16)(x >> 16);
}

// packed bf16 pair via compiler casts (emits v_cvt_pk_bf16_f32)
DEVI u32 pk2bf(float lo, float hi) {
  u16 l = __builtin_bit_cast(u16, (__bf16)lo);
  u16 h = __builtin_bit_cast(u16, (__bf16)hi);
  return (u32)l | ((u32)h << 16);
}

DEVI f32x4 mfma_bf16(s16x8 a, s16x8 b, f32x4 c) {
  return __builtin_amdgcn_mfma_f32_16x16x32_bf16(
      __builtin_bit_cast(bf16x8, a), __builtin_bit_cast(bf16x8, b), c, 0, 0, 0);
}

DEVI f32x16 mfma32(s16x8 a, s16x8 b, f32x16 c) {
  return __builtin_amdgcn_mfma_f32_32x32x16_bf16(
      __builtin_bit_cast(bf16x8, a), __builtin_bit_cast(bf16x8, b), c, 0, 0, 0);
}

DEVI void gload_lds16(const void* g, void* l) {
  __builtin_amdgcn_global_load_lds(
      (const __attribute__((address_space(1))) void*)g,
      (__attribute__((address_space(3))) void*)l, 16, 0, 0);
}

// ---------------------------------------------------------------------------
// Kernel 0: bit-pack KEEP bits.  int32[8][2048][2048] -> u64[8][32][2048]
// word (b,kt,q): bit l == 1  iff  kv = kt*64+l is KEPT (mask == 0).
// ---------------------------------------------------------------------------
__global__ __launch_bounds__(256)
void mask_pack(const int* __restrict__ mask, u64* __restrict__ mp) {
  const int t = threadIdx.x, lane = t & 63;
  const int gw = blockIdx.x * 4 + (t >> 6);
  const int kt = gw & 31, q = (gw >> 5) & 2047, b = gw >> 16;
  int mv = mask[((size_t)b * 2048 + q) * 2048 + kt * 64 + lane];
  u64 bits = __ballot(mv == 0);
  if (lane == 0) mp[((size_t)b * 32 + kt) * 2048 + q] = bits;
}

// ---------------------------------------------------------------------------
// Kernel 1: QKV projections.  z=0: Q=xq*wq^T+bq (scaled 1/8*log2e, bf16)
//           z=1: K           z=2: V written transposed as VT[b*512+h*64+d][s]
// ---------------------------------------------------------------------------
__global__ __launch_bounds__(256, 2)
void qkv_proj(const float* __restrict__ xq, const float* __restrict__ xkv,
              const float* __restrict__ wq, const float* __restrict__ bq,
              const float* __restrict__ wk, const float* __restrict__ bk,
              const float* __restrict__ wv, const float* __restrict__ bv,
              u16* __restrict__ Qo, u16* __restrict__ Ko, u16* __restrict__ VTo)
{
  __shared__ __align__(16) char smem[128 * 272]; // A[0,8K) B[8K,16K); V-transpose
  char* lds_a = smem;
  char* lds_b = smem + 8192;

  const int z = blockIdx.z;
  const float* X  = (z == 0) ? xq : xkv;
  const float* W  = (z == 0) ? wq : (z == 1 ? wk : wv);
  const float* Bv = (z == 0) ? bq : (z == 1 ? bk : bv);

  const int m0 = blockIdx.x * 128, n0 = blockIdx.y * 128;
  const int t = threadIdx.x, lane = t & 63, w = t >> 6;
  const int wr = w >> 1, wc = w & 1, g = lane >> 4, q15 = lane & 15;
  const int srow = t >> 1, shalf = t & 1;

  f32x4 acc[4][4];
  #pragma unroll
  for (int i = 0; i < 4; ++i)
    #pragma unroll
    for (int j = 0; j < 4; ++j) acc[i][j] = (f32x4){0.f, 0.f, 0.f, 0.f};

  const float* gA = X + (size_t)(m0 + srow) * 512 + shalf * 16;
  const float* gB = W + (size_t)(n0 + srow) * 512 + shalf * 16;
  const int wbyte = srow * 64;
  const int sw = (srow & 3) << 4;

  #pragma unroll 1
  for (int kt = 0; kt < 16; ++kt) {
    float4 fa[4], fb[4];
    #pragma unroll
    for (int j = 0; j < 4; ++j) {
      fa[j] = *(const float4*)(gA + kt * 32 + j * 4);
      fb[j] = *(const float4*)(gB + kt * 32 + j * 4);
    }
    __syncthreads();                    // prev compute done before overwrite
    const float* pfa = (const float*)fa;
    const float* pfb = (const float*)fb;
    s16x8 va[2], vb[2];
    #pragma unroll
    for (int half = 0; half < 2; ++half)
      #pragma unroll
      for (int e = 0; e < 8; ++e) {
        va[half][e] = (short)f2bf(pfa[half * 8 + e]);
        vb[half][e] = (short)f2bf(pfb[half * 8 + e]);
      }
    #pragma unroll
    for (int half = 0; half < 2; ++half) {
      *(s16x8*)(lds_a + wbyte + ((shalf * 32 + half * 16) ^ sw)) = va[half];
      *(s16x8*)(lds_b + wbyte + ((shalf * 32 + half * 16) ^ sw)) = vb[half];
    }
    __syncthreads();
    s16x8 afr[4], bfr[4];
    #pragma unroll
    for (int mi = 0; mi < 4; ++mi) {
      int row = wr * 64 + mi * 16 + q15;
      afr[mi] = *(const s16x8*)(lds_a + row * 64 + ((g * 16) ^ ((row & 3) << 4)));
    }
    #pragma unroll
    for (int ni = 0; ni < 4; ++ni) {
      int row = wc * 64 + ni * 16 + q15;
      bfr[ni] = *(const s16x8*)(lds_b + row * 64 + ((g * 16) ^ ((row & 3) << 4)));
    }
    #pragma unroll
    for (int mi = 0; mi < 4; ++mi)
      #pragma unroll
      for (int ni = 0; ni < 4; ++ni)
        acc[mi][ni] = mfma_bf16(afr[mi], bfr[ni], acc[mi][ni]);
  }

  float bias[4];
  #pragma unroll
  for (int ni = 0; ni < 4; ++ni) bias[ni] = Bv[n0 + wc * 64 + ni * 16 + q15];

  if (z < 2) {
    u16* Out = z ? Ko : Qo;
    // Q: fold 1/sqrt(64) * log2(e) so attention works in exp2 domain
    const float scale = z ? 1.0f : 0.18033688011112042f;
    #pragma unroll
    for (int mi = 0; mi < 4; ++mi)
      #pragma unroll
      for (int ni = 0; ni < 4; ++ni)
        #pragma unroll
        for (int r = 0; r < 4; ++r) {
          int m = m0 + wr * 64 + mi * 16 + g * 4 + r;
          int n = n0 + wc * 64 + ni * 16 + q15;
          Out[(size_t)m * 512 + n] = f2bf((acc[mi][ni][r] + bias[ni]) * scale);
        }
  } else {
    __syncthreads();                    // all frag reads done; reuse smem
    #pragma unroll
    for (int mi = 0; mi < 4; ++mi)
      #pragma unroll
      for (int ni = 0; ni < 4; ++ni)
        #pragma unroll
        for (int r = 0; r < 4; ++r) {
          int ml = wr * 64 + mi * 16 + g * 4 + r;
          int nl = wc * 64 + ni * 16 + q15;
          *(u16*)(smem + nl * 272 + ml * 2) = f2bf(acc[mi][ni][r] + bias[ni]);
        }
    __syncthreads();
    const int b  = m0 >> 11;
    const int s0 = m0 & 2047;
    #pragma unroll
    for (int nn = 0; nn < 2; ++nn) {
      int n  = nn * 64 + (t >> 2);
      int q4 = t & 3;
      u16* dst = VTo + (size_t)(b * 512 + n0 + n) * 2048 + s0 + q4 * 32;
      #pragma unroll
      for (int jj = 0; jj < 4; ++jj)
        *(s16x8*)(dst + jj * 8) = *(const s16x8*)(smem + n * 272 + q4 * 64 + jj * 16);
    }
  }
}

// ---------------------------------------------------------------------------
// Kernel 2: fused flash attention, 32x32 MFMA form.
// S^T = mfma32(K, Q): D[kv][q]; lane (q=lane&31, hi=lane>>5) owns
// kv = (reg&3)+8*(reg>>2)+4*hi (+32*tile).  P->A-frag exchange needs only
// lane^32 moves: per j two v_permlane32_swap of statically-indexed cvt_pk
// words.  No-max exp2 softmax, keep-bit masking, double-buffered K/V.
// grid.x = h + 8*b + 64*qt; block 256 = 4 waves x 32 q-rows.
// ---------------------------------------------------------------------------
__global__ __launch_bounds__(256, 2)
void attn_fwd(const u16* __restrict__ Q, const u16* __restrict__ K,
              const u16* __restrict__ VT, const u64* __restrict__ MP,
              float* __restrict__ out)
{
  __shared__ __align__(16) char lds_k[2][8192];  // [kv 64][d 64] bf16, swizzled
  __shared__ __align__(16) char lds_v[2][8192];  // [d 64][kv 64] bf16, swizzled

  const int bid = blockIdx.x;
  const int h = bid & 7, b = (bid >> 3) & 7, qt = bid >> 6;
  const int t = threadIdx.x, lane = t & 63, w = t >> 6;
  const int l31 = lane & 31, hi = lane >> 5;
  const int qbase = qt * 128 + w * 32;
  const int swz = (l31 & 7) << 4;

  // Q B-frags (pre-scaled by 0.125*log2e): col=q=l31, k(d) = j*16 + 8*hi + e
  s16x8 qf[4];
  #pragma unroll
  for (int j = 0; j < 4; ++j)
    qf[j] = *(const s16x8*)(Q + (size_t)(b * 2048 + qbase + l31) * 512
                              + h * 64 + j * 16 + hi * 8);
  asm volatile("" ::: "memory");        // pin qf loads before STAGE(0)

  f32x16 o0 = {0.f,0.f,0.f,0.f,0.f,0.f,0.f,0.f,0.f,0.f,0.f,0.f,0.f,0.f,0.f,0.f};
  f32x16 o1 = o0;
  const f32x16 ZZ = o0;
  float lrun = 0.f;

  const int srow8 = lane >> 3, slot = lane & 7;
  const u64* MPb = MP + (size_t)b * 32 * 2048;
  const int qrow = qbase + l31;

#define STAGE(kt_, buf_) do {                                                  \
    const int kv0_ = (kt_) * 64;                                               \
    _Pragma("unroll")                                                          \
    for (int i_ = 0; i_ < 2; ++i_) {                                           \
      int rl_ = w * 16 + i_ * 8 + srow8;                                       \
      gload_lds16(K + (size_t)(b * 2048 + kv0_ + rl_) * 512 + h * 64           \
                      + ((slot ^ (rl_ & 7)) * 8),                              \
                  &lds_k[buf_][w * 2048 + i_ * 1024]);                         \
      gload_lds16(VT + (size_t)(b * 512 + h * 64 + rl_) * 2048 + kv0_         \
                      + ((slot ^ (rl_ & 7)) * 8),                              \
                  &lds_v[buf_][w * 2048 + i_ * 1024]);                         \
    } } while (0)

  STAGE(0, 0);
  asm volatile("" ::: "memory");        // stage(0) issued before mask prefetch
  u64 pm = MPb[qrow];

  #pragma unroll 1
  for (int kt = 0; kt < 32; ++kt) {
    const int cur = kt & 1;
    const u64 kw = pm;
    if (kt + 1 < 32) {
      STAGE(kt + 1, cur ^ 1);
      asm volatile("" ::: "memory");
      pm = MPb[(kt + 1) * 2048 + qrow];
      // newer than {stage(kt), mask(kt)}: stage(kt+1)=4 + mask(kt+1)=1 = 5
      asm volatile("s_waitcnt vmcnt(5)" ::: "memory");
    } else {
      asm volatile("s_waitcnt vmcnt(0)" ::: "memory");
    }
    asm volatile("s_barrier" ::: "memory");

    // ---- S^T = K * Q^T over d=64 (4 mfma per kv-32 tile) ----
    f32x16 p0, p1;
    {
      s16x8 a0 = *(const s16x8*)(&lds_k[cur][ l31       * 128 + ((0 * 32 + hi * 16) ^ swz)]);
      s16x8 a1 = *(const s16x8*)(&lds_k[cur][(l31 + 32) * 128 + ((0 * 32 + hi * 16) ^ swz)]);
      p0 = mfma32(a0, qf[0], ZZ);
      p1 = mfma32(a1, qf[0], ZZ);
    }
    #pragma unroll
    for (int j = 1; j < 4; ++j) {
      s16x8 a0 = *(const s16x8*)(&lds_k[cur][ l31       * 128 + ((j * 32 + hi * 16) ^ swz)]);
      s16x8 a1 = *(const s16x8*)(&lds_k[cur][(l31 + 32) * 128 + ((j * 32 + hi * 16) ^ swz)]);
      p0 = mfma32(a0, qf[j], p0);
      p1 = mfma32(a1, qf[j], p1);
    }

    // ---- masked exp2, row-partial sum, pack to bf16 words ----
    // own kv of word (t2,q): 32*t2 + 8*(q>>1) + 2*(q&1) + 4*hi (+0/+1)
    u64 kws = kw >> (hi * 4);
    u32 mm0 = (u32)kws, mm1 = (u32)(kws >> 32);
    u32 wds[16];
    float lsum = 0.f;
    #pragma unroll
    for (int t2 = 0; t2 < 2; ++t2) {
      const u32 mmw = t2 ? mm1 : mm0;
      #pragma unroll
      for (int q = 0; q < 8; ++q) {
        const int bp = 8 * (q >> 1) + 2 * (q & 1);
        float s0v = t2 ? p1[2 * q] : p0[2 * q];
        float s1v = t2 ? p1[2 * q + 1] : p0[2 * q + 1];
        float e0 = exp2f(s0v), e1 = exp2f(s1v);
        u32 k0 = (u32)((int)(mmw << (31 - bp)) >> 31);        // sext bit bp
        u32 k1 = (u32)((int)(mmw << (30 - bp)) >> 31);        // sext bit bp+1
        e0 = __builtin_bit_cast(float, __builtin_bit_cast(u32, e0) & k0);
        e1 = __builtin_bit_cast(float, __builtin_bit_cast(u32, e1) & k1);
        lsum += e0; lsum += e1;
        wds[t2 * 8 + q] = pk2bf(e0, e1);
      }
    }
    lrun += lsum;

    // ---- PV: per j exchange 2 word-pairs across lane^32, then 2 mfma ----
    #pragma unroll
    for (int j = 0; j < 4; ++j) {
      const int ia = 2 * j, ib = 2 * j + 1;
      u32 wa0 = wds[(ia >> 2) * 8 + 2 * (ia & 3)];
      u32 wa1 = wds[(ia >> 2) * 8 + 2 * (ia & 3) + 1];
      u32 wb0 = wds[(ib >> 2) * 8 + 2 * (ib & 3)];
      u32 wb1 = wds[(ib >> 2) * 8 + 2 * (ib & 3) + 1];
      // vdst[32:63] <-> src[0:31]: after swap
      //  wa = hi? partner-B : own-A  (= A-frag k-slots 0..1 -> Wd0)
      //  wb = hi? own-B     : partner-A (= k-slots 4..5 -> Wd2)
      asm("v_permlane32_swap_b32 %0, %1" : "+v"(wa0), "+v"(wb0));
      asm("v_permlane32_swap_b32 %0, %1" : "+v"(wa1), "+v"(wb1));
      u32x4 aw = {wa0, wa1, wb0, wb1};
      s16x8 af = __builtin_bit_cast(s16x8, aw);
      s16x8 v0 = *(const s16x8*)(&lds_v[cur][ l31       * 128 + ((j * 32 + hi * 16) ^ swz)]);
      s16x8 v1 = *(const s16x8*)(&lds_v[cur][(l31 + 32) * 128 + ((j * 32 + hi * 16) ^ swz)]);
      o0 = mfma32(af, v0, o0);
      o1 = mfma32(af, v1, o1);
    }

    asm volatile("s_waitcnt lgkmcnt(0)" ::: "memory");
    __builtin_amdgcn_sched_barrier(0);
    asm volatile("s_barrier" ::: "memory");   // reads done before next overwrite
  }

  // ---- epilogue: row sums (lane^32 halves hold disjoint kv), normalize ----
  lrun += __shfl_xor(lrun, 32);
  const float rq = 1.0f / lrun;                 // valid per q = l31 on all lanes
  #pragma unroll
  for (int reg = 0; reg < 16; ++reg) {
    const int ql = (reg & 3) + 8 * (reg >> 2) + 4 * hi;
    const float linv = __shfl(rq, ql);
    float* po = out + (size_t)(b * 2048 + qbase + ql) * 512 + h * 64 + l31;
    po[0]  = o0[reg] * linv;
    po[32] = o1[reg] * linv;
  }
}

extern "C" void kernel_launch(void* const* d_in, const int* in_sizes, int n_in,
                              void* d_out, int out_size, void* d_ws, size_t ws_size,
                              hipStream_t stream) {
  const float* xq  = (const float*)d_in[0];
  const float* xkv = (const float*)d_in[1];
  const int*   msk = (const int*)d_in[2];
  const float* wq  = (const float*)d_in[3];
  const float* bq  = (const float*)d_in[4];
  const float* wk  = (const float*)d_in[5];
  const float* bk  = (const float*)d_in[6];
  const float* wv  = (const float*)d_in[7];
  const float* bv  = (const float*)d_in[8];

  u16* Qw = (u16*)d_ws;                          // [16384][512] bf16 (x 0.1803)
  u16* Kw = Qw + (size_t)16384 * 512;            // [16384][512] bf16
  u16* VT = Kw + (size_t)16384 * 512;            // [4096][2048] bf16 (V^T)
  u64* MP = (u64*)(VT + (size_t)4096 * 2048);    // [8][32][2048] packed keep bits

  mask_pack<<<dim3(131072), 256, 0, stream>>>(msk, MP);
  qkv_proj<<<dim3(128, 4, 3), 256, 0, stream>>>(xq, xkv, wq, bq, wk, bk, wv, bv,
                                                Qw, Kw, VT);
  attn_fwd<<<dim3(1024), 256, 0, stream>>>(Qw, Kw, VT, MP, (float*)d_out);
}